// Round 1
// baseline (159.540 us; speedup 1.0000x reference)
//
#include <hip/hip_runtime.h>

#define LDIM 1024
#define NSHIFT 10

__global__ __launch_bounds__(256) void chunk_mask_kernel(
    const int* __restrict__ mask, int* __restrict__ out)
{
    const int i = blockIdx.x;   // row index within L
    const int b = blockIdx.y;   // batch index
    const int t = threadIdx.x;
    const int j0 = t << 2;      // first of 4 columns this thread writes

    const int* __restrict__ mrow = mask + (size_t)b * LDIM;

    int4 v = make_int4(0, 0, 0, 0);

    // Does [j0, j0+3] intersect the band [i-10, i+10]?
    if (j0 + 3 >= i - NSHIFT && j0 <= i + NSHIFT) {
        int vals[4];
#pragma unroll
        for (int u = 0; u < 4; ++u) {
            const int j = j0 + u;
            const int d = j - i;
            int val = 0;
            if (d >= -NSHIFT && d <= NSHIFT) {
                const int lo = (i < j) ? i : j;
                const int hi = (i < j) ? j : i;
                int s = 0;
                for (int k = lo + 1; k <= hi; ++k) s += mrow[k];
                val = (s == 0) ? 1 : 0;
            }
            vals[u] = val;
        }
        v = make_int4(vals[0], vals[1], vals[2], vals[3]);
    }

    int4* __restrict__ outv = (int4*)out;
    outv[((size_t)b * LDIM + i) * (LDIM / 4) + t] = v;
}

extern "C" void kernel_launch(void* const* d_in, const int* in_sizes, int n_in,
                              void* d_out, int out_size, void* d_ws, size_t ws_size,
                              hipStream_t stream) {
    const int* mask = (const int*)d_in[0];
    int* out = (int*)d_out;
    const int B = in_sizes[0] / LDIM;   // 32

    dim3 grid(LDIM, B);   // one block per (row, batch)
    dim3 block(256);
    chunk_mask_kernel<<<grid, block, 0, stream>>>(mask, out);
}